// Round 7
// baseline (17.575 us; speedup 1.0000x reference)
//
#include <hip/hip_runtime.h>

#define Bb 128
#define Cc 400
#define Ll 100
#define Pp 16
#define KP 128       // K padded to 4 MFMA k-steps
#define WS 136       // wT row stride (elements): 272B -> 2-way LDS conflict max

typedef __attribute__((ext_vector_type(8))) short short8;  // 8 bf16 (4 VGPR)
typedef __attribute__((ext_vector_type(4))) float f32x4;

// fp32 -> bf16, round-to-nearest-even, branchless
static __device__ __forceinline__ unsigned short f2bf(float f) {
  unsigned int u = __float_as_uint(f);
  u += 0x7fffu + ((u >> 16) & 1u);
  return (unsigned short)(u >> 16);
}

// ---------------------------------------------------------------------------
// MFMA formulation with x-prefetch and support-restricted weight compute.
//
// out[b] (400x16) = x[b] (400x100) . w[b] (100x16), per-batch w from closed
// form (support exactly i in [s,e]; e<=99 so the xmax clip never binds).
//
// Schedule per block: issue 8 global_load_dwordx4 (x tile) -> registers,
// THEN phase-1 VALU (closed form, skipped outside support) while loads fly,
// barrier, cvt x->bf16, 4 x mfma_f32_16x16x32_bf16, store.
//
// Fragment layouts (gfx950, §3): A: row=lane&15, k=8*(lane>>4)+j;
// B: col=lane&15 (wT row), same k; D: col=lane&15, row=4*(lane>>4)+v.
// ---------------------------------------------------------------------------
__global__ __launch_bounds__(256) void TemporalPooling_mfma_kernel(
    const float* __restrict__ x, const int* __restrict__ seg,
    float* __restrict__ out) {
  __shared__ unsigned short wT[Pp * WS];   // [l][i] bf16, 4352 B

  const int b    = blockIdx.y;
  const int tid  = threadIdx.x;
  const int wave = tid >> 6;
  const int lane = tid & 63;
  const int arow = lane & 15;
  const int g    = lane >> 4;
  const int tile = blockIdx.x * 4 + wave;   // 0..27; 25 real tiles
  const bool active = (tile < Cc / 16);

  const int s = seg[2 * b];
  const int e = seg[2 * b + 1];
  const int d = e - s;
  const float inv = 1.0f / (float)max(d, 1);

  // ---- prefetch x tile (raw f32) BEFORE phase 1; latency hides under it ----
  float4 xv[8];
#pragma unroll
  for (int t = 0; t < 4; ++t) {
    xv[2 * t]     = make_float4(0.f, 0.f, 0.f, 0.f);
    xv[2 * t + 1] = make_float4(0.f, 0.f, 0.f, 0.f);
  }
  if (active) {
    const float* xrow = x + ((size_t)b * Cc + tile * 16 + arow) * Ll;
#pragma unroll
    for (int t = 0; t < 4; ++t) {
      const int k0 = t * 32 + g * 8;
      if (k0 < Ll)     xv[2 * t]     = *(const float4*)(xrow + k0);
      if (k0 + 4 < Ll) xv[2 * t + 1] = *(const float4*)(xrow + k0 + 4);
    }
  }

  // ---- phase 1: weights into LDS, closed form only on support [s,e] ----
  for (int idx = tid; idx < Pp * KP; idx += 256) {
    const int i = idx >> 4;    // 0..127
    const int l = idx & 15;

    float sum = 0.0f;
    if (i >= s && i <= e) {    // outside support provably 0
      const int a  = 16 * s + d * l;
      const int ad = a + d;

      const int base1 = 16 * i;
      {  // i0 == i : q in [16i,16i+16) ∩ [a,ad) ∩ [0,1584)
        const int lo = max(base1, a);
        const int hi = min(min(base1 + 16, ad), 1584);
        const int n = hi - lo;
        if (n > 0) {
          const int sq = (hi * (hi - 1) - lo * (lo - 1)) >> 1;
          sum += (float)n - (float)(sq - n * base1) * 0.0625f;
        }
      }
      {  // i0 == i-1 : q in [16(i-1),16i) ∩ [a,ad) ∩ [0,1584)
        const int base2 = base1 - 16;
        const int lo = max(base2, a);
        const int hi = min(min(base1, ad), 1584);
        const int n = hi - lo;
        if (n > 0) {
          const int sq = (hi * (hi - 1) - lo * (lo - 1)) >> 1;
          sum += (float)(sq - n * base2) * 0.0625f;
        }
      }
      if (i == Ll - 1) {  // clip tail (never fires for e<=99; kept for safety)
        const int nclip = ad - max(a, 1584);
        if (nclip > 0) sum += (float)nclip;
      }
      sum *= inv;
    }
    wT[l * WS + i] = f2bf(sum);
  }
  __syncthreads();

  if (!active) return;

  // ---- phase 2: cvt + 4 MFMA ----
  f32x4 acc = {0.f, 0.f, 0.f, 0.f};
#pragma unroll
  for (int t = 0; t < 4; ++t) {
    short8 afrag;
    const float4 v0 = xv[2 * t], v1 = xv[2 * t + 1];
    afrag[0] = (short)f2bf(v0.x); afrag[1] = (short)f2bf(v0.y);
    afrag[2] = (short)f2bf(v0.z); afrag[3] = (short)f2bf(v0.w);
    afrag[4] = (short)f2bf(v1.x); afrag[5] = (short)f2bf(v1.y);
    afrag[6] = (short)f2bf(v1.z); afrag[7] = (short)f2bf(v1.w);

    const short8 bfrag =
        *(const short8*)&wT[arow * WS + t * 32 + g * 8];  // ds_read_b128

    acc = __builtin_amdgcn_mfma_f32_16x16x32_bf16(afrag, bfrag, acc, 0, 0, 0);
  }

  // ---- epilogue: D[row=4g+v][col=arow] -> out[b, tile*16+4g+v, arow] ----
  float* obase = out + (((size_t)b * Cc + tile * 16 + g * 4) * Pp) + arow;
#pragma unroll
  for (int v = 0; v < 4; ++v) obase[v * Pp] = acc[v];
}

extern "C" void kernel_launch(void* const* d_in, const int* in_sizes, int n_in,
                              void* d_out, int out_size, void* d_ws,
                              size_t ws_size, hipStream_t stream) {
  const float* x = (const float*)d_in[0];   // (128,400,100) fp32
  const int* seg = (const int*)d_in[1];     // (128,2) int32
  float* out = (float*)d_out;               // (128,400,16) fp32
  (void)d_ws; (void)ws_size;

  dim3 grid((Cc / 16 + 3) / 4, Bb);         // (7, 128)
  TemporalPooling_mfma_kernel<<<grid, 256, 0, stream>>>(x, seg, out);
}

// Round 8
// 14.334 us; speedup vs baseline: 1.2261x; 1.2261x over previous
//
#include <hip/hip_runtime.h>

#define Bb 128
#define Cc 400
#define Ll 100
#define Pp 16
#define KP 128       // K padded to 4 MFMA k-steps

typedef __attribute__((ext_vector_type(8))) short short8;  // 8 bf16 (4 VGPR)
typedef __attribute__((ext_vector_type(4))) float f32x4;

// fp32 -> bf16, round-to-nearest-even, branchless
static __device__ __forceinline__ unsigned short f2bf(float f) {
  unsigned int u = __float_as_uint(f);
  u += 0x7fffu + ((u >> 16) & 1u);
  return (unsigned short)(u >> 16);
}

// ---------------------------------------------------------------------------
// Kernel A: w[b][l][i] (bf16, i padded to 128) via closed form, ONE entry per
// thread. 128 batches x 2048 entries; grid (8,128) x 256 threads.
//
// Closed form (per b,l): q_j = 16*s + d*l + j (j in [0,d)),
// t=(min(q+8,1592)-8)/16, i0=min(floor(t),98), fr=t-i0;
// w[i] = [sum_{i0==i}(1-fr) + sum_{i0==i-1}(fr)] / max(d,1);
// each piece a contiguous q-range -> triangular-number sums.
// ---------------------------------------------------------------------------
__global__ __launch_bounds__(256) void wgen_kernel(
    const int* __restrict__ seg, unsigned short* __restrict__ w) {
  const int b   = blockIdx.y;
  const int idx = blockIdx.x * 256 + threadIdx.x;  // 0..2047
  const int l = idx >> 7;    // 0..15
  const int i = idx & 127;   // 0..127 (>=100 -> closed form yields 0)

  const int s = seg[2 * b];
  const int e = seg[2 * b + 1];
  const int d = e - s;
  const float inv = 1.0f / (float)max(d, 1);

  const int a  = 16 * s + d * l;
  const int ad = a + d;

  float sum = 0.0f;
  const int base1 = 16 * i;
  {  // i0 == i : q in [16i,16i+16) ∩ [a,ad) ∩ [0,1584)
    const int lo = max(base1, a);
    const int hi = min(min(base1 + 16, ad), 1584);
    const int n = hi - lo;
    if (n > 0) {
      const int sq = (hi * (hi - 1) - lo * (lo - 1)) >> 1;
      sum += (float)n - (float)(sq - n * base1) * 0.0625f;
    }
  }
  {  // i0 == i-1 : q in [16(i-1),16i) ∩ [a,ad) ∩ [0,1584)
    const int base2 = base1 - 16;
    const int lo = max(base2, a);
    const int hi = min(min(base1, ad), 1584);
    const int n = hi - lo;
    if (n > 0) {
      const int sq = (hi * (hi - 1) - lo * (lo - 1)) >> 1;
      sum += (float)(sq - n * base2) * 0.0625f;
    }
  }
  if (i == Ll - 1) {  // clip tail (never fires for e<=99; kept for safety)
    const int nclip = ad - max(a, 1584);
    if (nclip > 0) sum += (float)nclip;
  }

  w[(size_t)b * (Pp * KP) + idx] = f2bf(sum * inv);
}

// ---------------------------------------------------------------------------
// Kernel B: out[b] (400x16) = x[b] (400x100) . w[b]^T. One 16x16 tile per
// 64-thread block — no LDS, no barrier. 12 loads issue up front, 4 MFMAs.
//
// Fragment layouts (gfx950, §3, m89-verified): A: row=lane&15, k=8*(lane>>4)+j;
// B: col=lane&15 (w row l), same k; D: col=lane&15, row=4*(lane>>4)+v.
// ---------------------------------------------------------------------------
__global__ __launch_bounds__(64) void pool_mfma_kernel(
    const float* __restrict__ x, const unsigned short* __restrict__ w,
    float* __restrict__ out) {
  const int b    = blockIdx.y;
  const int tile = blockIdx.x;        // 0..24
  const int lane = threadIdx.x;       // 0..63
  const int arow = lane & 15;         // A row (channel) / B & D column (l)
  const int g    = lane >> 4;         // k-group

  const float* xrow = x + ((size_t)b * Cc + tile * 16 + arow) * Ll;
  const unsigned short* wrow = w + (size_t)b * (Pp * KP) + arow * KP;

  // x tile: 8 float4 (k0<Ll guards constant-per-lane after unroll)
  float4 xv[8];
#pragma unroll
  for (int t = 0; t < 4; ++t) {
    const int k0 = t * 32 + g * 8;
    xv[2 * t]     = (k0 < Ll)     ? *(const float4*)(xrow + k0)
                                  : make_float4(0.f, 0.f, 0.f, 0.f);
    xv[2 * t + 1] = (k0 + 4 < Ll) ? *(const float4*)(xrow + k0 + 4)
                                  : make_float4(0.f, 0.f, 0.f, 0.f);
  }
  // w fragments: 4 x 16B from L2-resident w
  short8 bf[4];
#pragma unroll
  for (int t = 0; t < 4; ++t)
    bf[t] = *(const short8*)(wrow + t * 32 + g * 8);

  f32x4 acc = {0.f, 0.f, 0.f, 0.f};
#pragma unroll
  for (int t = 0; t < 4; ++t) {
    const float4 v0 = xv[2 * t], v1 = xv[2 * t + 1];
    short8 af;
    af[0] = (short)f2bf(v0.x); af[1] = (short)f2bf(v0.y);
    af[2] = (short)f2bf(v0.z); af[3] = (short)f2bf(v0.w);
    af[4] = (short)f2bf(v1.x); af[5] = (short)f2bf(v1.y);
    af[6] = (short)f2bf(v1.z); af[7] = (short)f2bf(v1.w);
    acc = __builtin_amdgcn_mfma_f32_16x16x32_bf16(af, bf[t], acc, 0, 0, 0);
  }

  // D[row=4g+v][col=arow] -> out[b, tile*16+4g+v, arow]
  float* obase = out + (((size_t)b * Cc + tile * 16 + g * 4) * Pp) + arow;
#pragma unroll
  for (int v = 0; v < 4; ++v) obase[v * Pp] = acc[v];
}

extern "C" void kernel_launch(void* const* d_in, const int* in_sizes, int n_in,
                              void* d_out, int out_size, void* d_ws,
                              size_t ws_size, hipStream_t stream) {
  const float* x = (const float*)d_in[0];       // (128,400,100) fp32
  const int* seg = (const int*)d_in[1];         // (128,2) int32
  float* out = (float*)d_out;                   // (128,400,16) fp32
  unsigned short* w = (unsigned short*)d_ws;    // 128*16*128 bf16 = 512 KiB

  wgen_kernel<<<dim3(8, Bb), 256, 0, stream>>>(seg, w);
  pool_mfma_kernel<<<dim3(Cc / 16, Bb), 64, 0, stream>>>(x, w, out);
}

// Round 9
// 10.259 us; speedup vs baseline: 1.7131x; 1.3972x over previous
//
#include <hip/hip_runtime.h>

#define Bb 128
#define Cc 400
#define Ll 100
#define Pp 16
#define KP 128       // K padded to 4 MFMA k-steps
#define WS 136       // wT row stride (elements): 272B -> 2-way conflict max

typedef __attribute__((ext_vector_type(8))) short short8;  // 8 bf16 (4 VGPR)
typedef __attribute__((ext_vector_type(4))) float f32x4;
typedef unsigned int u32;
typedef const __attribute__((address_space(1))) u32* gas_p;
typedef __attribute__((address_space(3))) u32* las_p;

// fp32 -> bf16, round-to-nearest-even, branchless
static __device__ __forceinline__ unsigned short f2bf(float f) {
  unsigned int u = __float_as_uint(f);
  u += 0x7fffu + ((u >> 16) & 1u);
  return (unsigned short)(u >> 16);
}

// ---------------------------------------------------------------------------
// R6 structure + async x staging.
// Per block (batch b, 4 tiles of 16 channels):
//   1. issue global_load_lds DMA of each wave's 16x100 x-tile (6400B
//      contiguous) into LDS — zero VGPR cost, cannot be sunk by compiler
//   2. phase 1: closed-form w -> bf16 wT[l][i] in LDS (flat, unguarded —
//      R7 proved guards regress); DMA flies underneath
//   3. __syncthreads (drains vmcnt) 
//   4. phase 2: A-frags from x_lds (ds_read_b128), B-frags from wT,
//      4 x mfma_f32_16x16x32_bf16, coalesced store.
//
// Fragment layouts (gfx950, §3, m89-verified): A: row=lane&15, k=8*(lane>>4)+j;
// B: col=lane&15 (wT row l), same k; D: col=lane&15, row=4*(lane>>4)+v.
//
// Weight closed form (per b,l): q_j = 16*s + d*l + j (j in [0,d)),
// t=(min(q+8,1592)-8)/16, i0=min(floor(t),98), fr=t-i0;
// w[i] = [sum_{i0==i}(1-fr) + sum_{i0==i-1}(fr)] / max(d,1);
// contiguous q-ranges -> triangular-number sums.
// ---------------------------------------------------------------------------
__global__ __launch_bounds__(256) void TemporalPooling_mfma_kernel(
    const float* __restrict__ x, const int* __restrict__ seg,
    float* __restrict__ out) {
  __shared__ unsigned short wT[Pp * WS];     // [l][i] bf16, 4352 B
  __shared__ float xls[4][16 * Ll];          // per-wave 16x100 f32, 25.6 KiB

  const int b    = blockIdx.y;
  const int tid  = threadIdx.x;
  const int wave = tid >> 6;
  const int lane = tid & 63;
  const int arow = lane & 15;
  const int g    = lane >> 4;
  const int tile = blockIdx.x * 4 + wave;    // 0..27; 25 real
  const bool active = (tile < Cc / 16);
  const int tload = active ? tile : (Cc / 16 - 1);  // clamp: no OOB DMA

  // ---- 0: async DMA x tile -> LDS (6400B = 6x1024 + 256 tail) ----
  {
    const float* gsrc = x + ((size_t)b * Cc + tload * 16) * Ll;
    float* lbase = &xls[wave][0];
#pragma unroll
    for (int m = 0; m < 6; ++m) {
      __builtin_amdgcn_global_load_lds((gas_p)(gsrc + m * 256 + lane * 4),
                                       (las_p)(lbase + m * 256), 16, 0, 0);
    }
    if (lane < 16) {
      __builtin_amdgcn_global_load_lds((gas_p)(gsrc + 6 * 256 + lane * 4),
                                       (las_p)(lbase + 6 * 256), 16, 0, 0);
    }
  }

  // ---- 1: weights into LDS (flat closed form, 8 entries/thread) ----
  const int s = seg[2 * b];
  const int e = seg[2 * b + 1];
  const int d = e - s;
  const float inv = 1.0f / (float)max(d, 1);

  for (int idx = tid; idx < Pp * KP; idx += 256) {
    const int i = idx >> 4;    // 0..127 (>=100 -> 0 naturally)
    const int l = idx & 15;

    const int a  = 16 * s + d * l;
    const int ad = a + d;

    float sum = 0.0f;
    const int base1 = 16 * i;
    {  // i0 == i : q in [16i,16i+16) ∩ [a,ad) ∩ [0,1584)
      const int lo = max(base1, a);
      const int hi = min(min(base1 + 16, ad), 1584);
      const int n = hi - lo;
      if (n > 0) {
        const int sq = (hi * (hi - 1) - lo * (lo - 1)) >> 1;
        sum += (float)n - (float)(sq - n * base1) * 0.0625f;
      }
    }
    {  // i0 == i-1 : q in [16(i-1),16i) ∩ [a,ad) ∩ [0,1584)
      const int base2 = base1 - 16;
      const int lo = max(base2, a);
      const int hi = min(min(base1, ad), 1584);
      const int n = hi - lo;
      if (n > 0) {
        const int sq = (hi * (hi - 1) - lo * (lo - 1)) >> 1;
        sum += (float)(sq - n * base2) * 0.0625f;
      }
    }
    if (i == Ll - 1) {  // clip tail (never fires for e<=99; safety)
      const int nclip = ad - max(a, 1584);
      if (nclip > 0) sum += (float)nclip;
    }

    wT[l * WS + i] = f2bf(sum * inv);
  }
  __syncthreads();   // also drains vmcnt(0): DMA complete

  if (!active) return;

  // ---- 2: A from x_lds, B from wT, 4 MFMA ----
  const float* xrow = &xls[wave][arow * Ll];

  f32x4 acc = {0.f, 0.f, 0.f, 0.f};
#pragma unroll
  for (int t = 0; t < 4; ++t) {
    const int k0 = t * 32 + g * 8;
    float xf[8];
    if (t < 3) {                                  // k0..k0+7 <= 95 valid
      const float4 v0 = *(const float4*)(xrow + k0);
      const float4 v1 = *(const float4*)(xrow + k0 + 4);
      xf[0] = v0.x; xf[1] = v0.y; xf[2] = v0.z; xf[3] = v0.w;
      xf[4] = v1.x; xf[5] = v1.y; xf[6] = v1.z; xf[7] = v1.w;
    } else {                                      // t=3: only g=0 has k<100
      xf[0] = xf[1] = xf[2] = xf[3] = 0.f;
      xf[4] = xf[5] = xf[6] = xf[7] = 0.f;
      if (g == 0) {
        const float4 v0 = *(const float4*)(xrow + 96);
        xf[0] = v0.x; xf[1] = v0.y; xf[2] = v0.z; xf[3] = v0.w;
      }
    }

    short8 af;
#pragma unroll
    for (int j = 0; j < 8; ++j) af[j] = (short)f2bf(xf[j]);

    const short8 bf =
        *(const short8*)&wT[arow * WS + t * 32 + g * 8];  // ds_read_b128

    acc = __builtin_amdgcn_mfma_f32_16x16x32_bf16(af, bf, acc, 0, 0, 0);
  }

  // ---- epilogue: D[row=4g+v][col=arow] -> out[b, tile*16+4g+v, arow] ----
  float* obase = out + (((size_t)b * Cc + tile * 16 + g * 4) * Pp) + arow;
#pragma unroll
  for (int v = 0; v < 4; ++v) obase[v * Pp] = acc[v];
}

extern "C" void kernel_launch(void* const* d_in, const int* in_sizes, int n_in,
                              void* d_out, int out_size, void* d_ws,
                              size_t ws_size, hipStream_t stream) {
  const float* x = (const float*)d_in[0];   // (128,400,100) fp32
  const int* seg = (const int*)d_in[1];     // (128,2) int32
  float* out = (float*)d_out;               // (128,400,16) fp32
  (void)d_ws; (void)ws_size;

  dim3 grid((Cc / 16 + 3) / 4, Bb);         // (7, 128)
  TemporalPooling_mfma_kernel<<<grid, 256, 0, stream>>>(x, seg, out);
}

// Round 10
// 10.046 us; speedup vs baseline: 1.7494x; 1.0212x over previous
//
#include <hip/hip_runtime.h>

#define Bb 128
#define Cc 400
#define Ll 100
#define Pp 16
#define KP 128       // K padded to 4 MFMA k-steps
#define WS 136       // wT row stride (elements): 272B -> 2-way conflict max

typedef __attribute__((ext_vector_type(8))) short short8;  // 8 bf16 (4 VGPR)
typedef __attribute__((ext_vector_type(4))) float f32x4;
typedef unsigned int u32;
typedef const __attribute__((address_space(1))) u32* gas_p;
typedef __attribute__((address_space(3))) u32* las_p;

// fp32 -> bf16, round-to-nearest-even, branchless
static __device__ __forceinline__ unsigned short f2bf(float f) {
  unsigned int u = __float_as_uint(f);
  u += 0x7fffu + ((u >> 16) & 1u);
  return (unsigned short)(u >> 16);
}

// ---------------------------------------------------------------------------
// R9 structure, widened to 8-wave blocks:
//   grid (4,128) x 512 thr: phase-1 redundancy 7x -> 4x per batch, 4 (not 8)
//   closed-form entries per thread, 2 blocks/CU (4 waves/SIMD) so one block's
//   phase-2 overlaps the other's barrier drain. Inactive waves skip DMA.
//
// Per block: (0) async global_load_lds DMA of each active wave's 16x100
// x-tile (6400B contiguous) into LDS; (1) closed-form w -> bf16 wT[l][i] in
// LDS (flat, unguarded); (2) __syncthreads (drains vmcnt); (3) A-frags from
// x_lds, B-frags from wT, 4 x mfma_f32_16x16x32_bf16, coalesced store.
//
// Fragment layouts (gfx950, §3, m89-verified): A: row=lane&15, k=8*(lane>>4)+j;
// B: col=lane&15 (wT row l), same k; D: col=lane&15, row=4*(lane>>4)+v.
//
// Weight closed form (per b,l): q_j = 16*s + d*l + j (j in [0,d)),
// t=(min(q+8,1592)-8)/16, i0=min(floor(t),98), fr=t-i0;
// w[i] = [sum_{i0==i}(1-fr) + sum_{i0==i-1}(fr)] / max(d,1);
// contiguous q-ranges -> triangular-number sums.
// ---------------------------------------------------------------------------
__global__ __launch_bounds__(512) void TemporalPooling_mfma_kernel(
    const float* __restrict__ x, const int* __restrict__ seg,
    float* __restrict__ out) {
  __shared__ unsigned short wT[Pp * WS];     // [l][i] bf16, 4352 B
  __shared__ float xls[8][16 * Ll];          // per-wave 16x100 f32, 51.2 KiB

  const int b    = blockIdx.y;
  const int tid  = threadIdx.x;
  const int wave = tid >> 6;                 // 0..7
  const int lane = tid & 63;
  const int arow = lane & 15;
  const int g    = lane >> 4;
  const int tile = blockIdx.x * 8 + wave;    // 0..31; 25 real
  const bool active = (tile < Cc / 16);

  // ---- 0: async DMA x tile -> LDS (6400B = 6x1024 + 256 tail) ----
  if (active) {                              // wave-uniform branch
    const float* gsrc = x + ((size_t)b * Cc + tile * 16) * Ll;
    float* lbase = &xls[wave][0];
#pragma unroll
    for (int m = 0; m < 6; ++m) {
      __builtin_amdgcn_global_load_lds((gas_p)(gsrc + m * 256 + lane * 4),
                                       (las_p)(lbase + m * 256), 16, 0, 0);
    }
    if (lane < 16) {
      __builtin_amdgcn_global_load_lds((gas_p)(gsrc + 6 * 256 + lane * 4),
                                       (las_p)(lbase + 6 * 256), 16, 0, 0);
    }
  }

  // ---- 1: weights into LDS (flat closed form, 4 entries/thread) ----
  const int s = seg[2 * b];
  const int e = seg[2 * b + 1];
  const int d = e - s;
  const float inv = 1.0f / (float)max(d, 1);

  for (int idx = tid; idx < Pp * KP; idx += 512) {
    const int i = idx >> 4;    // 0..127 (>=100 -> 0 naturally)
    const int l = idx & 15;

    const int a  = 16 * s + d * l;
    const int ad = a + d;

    float sum = 0.0f;
    const int base1 = 16 * i;
    {  // i0 == i : q in [16i,16i+16) ∩ [a,ad) ∩ [0,1584)
      const int lo = max(base1, a);
      const int hi = min(min(base1 + 16, ad), 1584);
      const int n = hi - lo;
      if (n > 0) {
        const int sq = (hi * (hi - 1) - lo * (lo - 1)) >> 1;
        sum += (float)n - (float)(sq - n * base1) * 0.0625f;
      }
    }
    {  // i0 == i-1 : q in [16(i-1),16i) ∩ [a,ad) ∩ [0,1584)
      const int base2 = base1 - 16;
      const int lo = max(base2, a);
      const int hi = min(min(base1, ad), 1584);
      const int n = hi - lo;
      if (n > 0) {
        const int sq = (hi * (hi - 1) - lo * (lo - 1)) >> 1;
        sum += (float)(sq - n * base2) * 0.0625f;
      }
    }
    if (i == Ll - 1) {  // clip tail (never fires for e<=99; safety)
      const int nclip = ad - max(a, 1584);
      if (nclip > 0) sum += (float)nclip;
    }

    wT[l * WS + i] = f2bf(sum * inv);
  }
  __syncthreads();   // also drains vmcnt(0): DMA complete

  if (!active) return;

  // ---- 2: A from x_lds, B from wT, 4 MFMA ----
  const float* xrow = &xls[wave][arow * Ll];

  f32x4 acc = {0.f, 0.f, 0.f, 0.f};
#pragma unroll
  for (int t = 0; t < 4; ++t) {
    const int k0 = t * 32 + g * 8;
    float xf[8];
    if (t < 3) {                                  // k0..k0+7 <= 95 valid
      const float4 v0 = *(const float4*)(xrow + k0);
      const float4 v1 = *(const float4*)(xrow + k0 + 4);
      xf[0] = v0.x; xf[1] = v0.y; xf[2] = v0.z; xf[3] = v0.w;
      xf[4] = v1.x; xf[5] = v1.y; xf[6] = v1.z; xf[7] = v1.w;
    } else {                                      // t=3: only g=0 has k<100
      xf[0] = xf[1] = xf[2] = xf[3] = 0.f;
      xf[4] = xf[5] = xf[6] = xf[7] = 0.f;
      if (g == 0) {
        const float4 v0 = *(const float4*)(xrow + 96);
        xf[0] = v0.x; xf[1] = v0.y; xf[2] = v0.z; xf[3] = v0.w;
      }
    }

    short8 af;
#pragma unroll
    for (int j = 0; j < 8; ++j) af[j] = (short)f2bf(xf[j]);

    const short8 bf =
        *(const short8*)&wT[arow * WS + t * 32 + g * 8];  // ds_read_b128

    acc = __builtin_amdgcn_mfma_f32_16x16x32_bf16(af, bf, acc, 0, 0, 0);
  }

  // ---- epilogue: D[row=4g+v][col=arow] -> out[b, tile*16+4g+v, arow] ----
  float* obase = out + (((size_t)b * Cc + tile * 16 + g * 4) * Pp) + arow;
#pragma unroll
  for (int v = 0; v < 4; ++v) obase[v * Pp] = acc[v];
}

extern "C" void kernel_launch(void* const* d_in, const int* in_sizes, int n_in,
                              void* d_out, int out_size, void* d_ws,
                              size_t ws_size, hipStream_t stream) {
  const float* x = (const float*)d_in[0];   // (128,400,100) fp32
  const int* seg = (const int*)d_in[1];     // (128,2) int32
  float* out = (float*)d_out;               // (128,400,16) fp32
  (void)d_ws; (void)ws_size;

  dim3 grid(4, Bb);                         // 512 blocks, 8 waves each
  TemporalPooling_mfma_kernel<<<grid, 512, 0, stream>>>(x, seg, out);
}